// Round 1
// 200.834 us; speedup vs baseline: 1.2931x; 1.2931x over previous
//
#include <hip/hip_runtime.h>

// Problem constants (B=2, C=32, T=8, H=32, W=32, V=8192)
#define NQ    16384      // B*T*H*W
#define CDIM  32
#define VSZ   8192
#define PLANE 8192       // T*H*W
#define BSTR  262144     // C*PLANE
#define NEL   524288     // B*C*T*H*W
#define MARGIN 0.004f    // > 2x worst-case bf16x3 distance error (~1.6e-3)

typedef unsigned long long u64;
typedef unsigned int u32;
typedef unsigned short u16;
using f32x4 = __attribute__((ext_vector_type(4))) float;
using s16x8 = __attribute__((ext_vector_type(8))) short;

// order-preserving float->uint map (min dist, tie -> min idx when packed with idx)
__device__ __forceinline__ u32 flip_bits(u32 b) {
    return (b & 0x80000000u) ? ~b : (b | 0x80000000u);
}
__device__ __forceinline__ float unflip_val(u32 b) {
    u32 u = (b & 0x80000000u) ? (b ^ 0x80000000u) : ~b;
    return __uint_as_float(u);
}
__device__ __forceinline__ u16 bf16_rne(float x) {
    u32 u = __float_as_uint(x);
    return (u16)((u + 0x7fffu + ((u >> 16) & 1u)) >> 16);
}

// ---------------- K1: prep — bf16 hi/lo frag arrays + enorm + zeros ----------------
// Frag layout for mfma_f32_16x16x32_bf16 (m97-pattern): lane l holds
// A[row=l&15][k=(l>>4)*8 + i] (codes) / B[col=l&15][k=(l>>4)*8 + i] (queries).
// t < 32768        : EF (512 code tiles x 64 lanes), e plain
// 32768 <= t <98304: QF (1024 query subtiles x 64 lanes), q' = -2*q
// t >= 98304       : enorm + zero counts
__global__ void k_prep(const float* __restrict__ f, const float* __restrict__ emb,
                       u16* __restrict__ EFh, u16* __restrict__ EFl,
                       u16* __restrict__ QFh, u16* __restrict__ QFl,
                       float* __restrict__ enorm, int* __restrict__ counts,
                       float* __restrict__ loss_sum, int* __restrict__ uct,
                       int* __restrict__ flag) {
    int t = blockIdx.x * 256 + threadIdx.x;   // 416*256 = 106496
    if (t == 0) { *loss_sum = 0.f; *uct = 0; *flag = 0; }
    if (t < 32768) {
        int tile = t >> 6, l = t & 63;
        int row = tile * 16 + (l & 15);
        int k0 = (l >> 4) * 8;
        const float* src = emb + row * CDIM + k0;
        s16x8 vh, vl;
#pragma unroll
        for (int i = 0; i < 8; ++i) {
            float v = src[i];
            u16 hb = bf16_rne(v);
            float hf = __uint_as_float(((u32)hb) << 16);
            vh[i] = (short)hb;
            vl[i] = (short)bf16_rne(v - hf);
        }
        *(s16x8*)(EFh + t * 8) = vh;
        *(s16x8*)(EFl + t * 8) = vl;
    } else if (t < 98304) {
        int t2 = t - 32768;
        int st = t2 >> 6, l = t2 & 63;
        int n = st * 16 + (l & 15);
        int k0 = (l >> 4) * 8;
        int b = n >> 13, p = n & (PLANE - 1);
        const float* fq = f + b * BSTR + p;
        s16x8 vh, vl;
#pragma unroll
        for (int i = 0; i < 8; ++i) {
            float v = -2.0f * fq[(k0 + i) * PLANE];
            u16 hb = bf16_rne(v);
            float hf = __uint_as_float(((u32)hb) << 16);
            vh[i] = (short)hb;
            vl[i] = (short)bf16_rne(v - hf);
        }
        *(s16x8*)(QFh + t2 * 8) = vh;
        *(s16x8*)(QFl + t2 * 8) = vl;
    } else {
        int j = t - 98304;    // < 8192
        const float4* row = (const float4*)(emb + j * CDIM);
        float s = 0.f;
#pragma unroll
        for (int r = 0; r < 8; ++r) {
            float4 v = row[r];
            s += v.x * v.x + v.y * v.y + v.z * v.z + v.w * v.w;
        }
        enorm[j] = s;
        counts[j] = 0;
    }
}

// ---------------- K2: bf16x3 MFMA distance + per-query (min1,idx,min2) ----------------
// grid 2049 x 64 (1 wave). Block (wq,seg): queries wq*64..+63 (4 subtiles of 16,
// B-frags persistent in regs), codes seg*64..+64 tiles of 16 (A-frags streamed
// from L2-resident frag arrays; NO LDS). dist = enorm (exact fp32 C-init)
//   + ah*qh + ah*ql + al*qh   (missing lo*lo ~ 2^-17 rel).
// Block 2048 = layout self-check: on mismatch set flag -> k_final marks ALL
// queries uncertain -> k_exact resolves (slow-but-correct fallback).
__global__ __launch_bounds__(64) void k_mfma(
    const u16* __restrict__ QFh, const u16* __restrict__ QFl,
    const u16* __restrict__ EFh, const u16* __restrict__ EFl,
    const float* __restrict__ enorm,
    u64* __restrict__ PARTK, float* __restrict__ PARTM2,
    const float* __restrict__ f, const float* __restrict__ emb,
    int* __restrict__ flag) {
    const int l = threadIdx.x;
    const int lq = (l >> 4) * 4;   // D row-quad base: row = lq + r, col = l&15

    if (blockIdx.x == 2048) {
        // self-check: tile 0 (codes 0..15) x subtile 0 (queries 0..15)
        s16x8 ah = *(const s16x8*)(EFh + l * 8);
        s16x8 al = *(const s16x8*)(EFl + l * 8);
        s16x8 qh = *(const s16x8*)(QFh + l * 8);
        s16x8 ql = *(const s16x8*)(QFl + l * 8);
        f32x4 en = *(const f32x4*)(enorm + lq);
        f32x4 acc = __builtin_amdgcn_mfma_f32_16x16x32_bf16(ah, qh, en, 0, 0, 0);
        acc = __builtin_amdgcn_mfma_f32_16x16x32_bf16(ah, ql, acc, 0, 0, 0);
        acc = __builtin_amdgcn_mfma_f32_16x16x32_bf16(al, qh, acc, 0, 0, 0);
        int q = l & 15;                 // query n = q (b=0, p=q)
        const float* fq = f + q;
        int bad = 0;
#pragma unroll
        for (int r = 0; r < 4; ++r) {
            int code = lq + r;
            float ref = enorm[code];
            const float* er = emb + code * CDIM;
            for (int c = 0; c < CDIM; ++c)
                ref = fmaf(-2.0f * fq[c * PLANE], er[c], ref);
            if (fabsf(acc[r] - ref) > 0.05f) bad = 1;
        }
        if (bad) *flag = 1;
        return;
    }

    const int wq = blockIdx.x >> 3, seg = blockIdx.x & 7;
    s16x8 qh[4], ql[4];
#pragma unroll
    for (int s = 0; s < 4; ++s) {
        int st = wq * 4 + s;
        qh[s] = *(const s16x8*)(QFh + (st * 64 + l) * 8);
        ql[s] = *(const s16x8*)(QFl + (st * 64 + l) * 8);
    }
    float m1v[4], m2v[4]; int m1i[4];
#pragma unroll
    for (int s = 0; s < 4; ++s) { m1v[s] = 1e30f; m2v[s] = 1e30f; m1i[s] = 0; }

#pragma unroll 2
    for (int t = 0; t < 64; ++t) {
        int tile = seg * 64 + t;
        s16x8 ah = *(const s16x8*)(EFh + (tile * 64 + l) * 8);
        s16x8 al = *(const s16x8*)(EFl + (tile * 64 + l) * 8);
        f32x4 en = *(const f32x4*)(enorm + tile * 16 + lq);
        int bc = tile * 16 + lq;
#pragma unroll
        for (int s = 0; s < 4; ++s) {
            f32x4 acc = __builtin_amdgcn_mfma_f32_16x16x32_bf16(ah, qh[s], en, 0, 0, 0);
            acc = __builtin_amdgcn_mfma_f32_16x16x32_bf16(ah, ql[s], acc, 0, 0, 0);
            acc = __builtin_amdgcn_mfma_f32_16x16x32_bf16(al, qh[s], acc, 0, 0, 0);
#pragma unroll
            for (int r = 0; r < 4; ++r) {   // codes ascend with (t, r): strict < keeps first
                float v = acc[r];
                bool lt = v < m1v[s];
                float m2c = fminf(m2v[s], v);
                m2v[s] = lt ? m1v[s] : m2c;
                m1i[s] = lt ? (bc + r) : m1i[s];
                m1v[s] = fminf(m1v[s], v);
            }
        }
    }
    // merge lanes {l, l^16, l^32, l^48} (same query col), tournament-exact (m1,m2)
#pragma unroll
    for (int s = 0; s < 4; ++s) {
        u64 key = ((u64)flip_bits(__float_as_uint(m1v[s])) << 32) | (u32)m1i[s];
        float m2 = m2v[s];
#pragma unroll
        for (int off = 16; off <= 32; off <<= 1) {
            u64 ko = __shfl_xor(key, off, 64);
            float m2o = __shfl_xor(m2, off, 64);
            u64 kmax = ko > key ? ko : key;
            m2 = fminf(fminf(m2, m2o), unflip_val((u32)(kmax >> 32)));
            key = ko < key ? ko : key;
        }
        if (l < 16) {
            int q = wq * 64 + s * 16 + l;
            PARTK[seg * NQ + q] = key;
            PARTM2[seg * NQ + q] = m2;
        }
    }
}

// ---------------- K3: finalize — merge 8 segments, certainty test ----------------
__global__ void k_final(const u64* __restrict__ PARTK, const float* __restrict__ PARTM2,
                        int* __restrict__ out_idx, int* __restrict__ counts,
                        int* __restrict__ uct, int* __restrict__ ulist,
                        const int* __restrict__ flag) {
    int q = blockIdx.x * 256 + threadIdx.x;   // 16384
    u64 K = PARTK[q]; float M2 = PARTM2[q];
#pragma unroll
    for (int s = 1; s < 8; ++s) {
        u64 k = PARTK[s * NQ + q]; float m2 = PARTM2[s * NQ + q];
        u64 kmax = k > K ? k : K;
        M2 = fminf(fminf(M2, m2), unflip_val((u32)(kmax >> 32)));
        K = k < K ? k : K;
    }
    int idx = (int)(K & 0xffffffffull);
    float m1 = unflip_val((u32)(K >> 32));
    out_idx[q] = idx;
    if (M2 - m1 > MARGIN && *flag == 0) {
        atomicAdd(&counts[idx], 1);
    } else {
        int p = atomicAdd(uct, 1);   // bounded by NQ -> ulist never overflows
        ulist[p] = q;
    }
}

// ---------------- K4: exact fp32 rescan for uncertain queries (2 per block-pass) ----------------
__global__ __launch_bounds__(256) void k_exact(
    const int* __restrict__ ulist, const int* __restrict__ uct,
    const float* __restrict__ f, const float* __restrict__ emb,
    const float* __restrict__ enorm, int* __restrict__ out_idx,
    int* __restrict__ counts) {
    __shared__ u64 wred[4][2];
    const int tid = threadIdx.x;
    const int uc = *uct;
    for (int base = blockIdx.x * 2; base < uc; base += 256) {
        int nq = uc - base; if (nq > 2) nq = 2;
        int q0 = ulist[base];
        int q1 = (nq > 1) ? ulist[base + 1] : q0;
        float qv0[CDIM], qv1[CDIM];
        {
            const float* f0 = f + (q0 >> 13) * BSTR + (q0 & (PLANE - 1));
            const float* f1 = f + (q1 >> 13) * BSTR + (q1 & (PLANE - 1));
#pragma unroll
            for (int c = 0; c < CDIM; ++c) {
                qv0[c] = -2.0f * f0[c * PLANE];
                qv1[c] = -2.0f * f1[c * PLANE];
            }
        }
        u64 k0 = ~0ull, k1 = ~0ull;
        for (int jj = 0; jj < 32; ++jj) {
            int j = tid + 256 * jj;
            const float4* er = (const float4*)(emb + j * CDIM);
            float d0 = enorm[j], d1 = d0;
#pragma unroll
            for (int c4 = 0; c4 < 8; ++c4) {
                float4 v = er[c4];
                d0 = fmaf(qv0[c4 * 4 + 0], v.x, d0); d0 = fmaf(qv0[c4 * 4 + 1], v.y, d0);
                d0 = fmaf(qv0[c4 * 4 + 2], v.z, d0); d0 = fmaf(qv0[c4 * 4 + 3], v.w, d0);
                d1 = fmaf(qv1[c4 * 4 + 0], v.x, d1); d1 = fmaf(qv1[c4 * 4 + 1], v.y, d1);
                d1 = fmaf(qv1[c4 * 4 + 2], v.z, d1); d1 = fmaf(qv1[c4 * 4 + 3], v.w, d1);
            }
            u64 nk0 = ((u64)flip_bits(__float_as_uint(d0)) << 32) | (u32)j;
            u64 nk1 = ((u64)flip_bits(__float_as_uint(d1)) << 32) | (u32)j;
            if (nk0 < k0) k0 = nk0;
            if (nk1 < k1) k1 = nk1;
        }
#pragma unroll
        for (int off = 1; off <= 32; off <<= 1) {
            u64 o0 = __shfl_xor(k0, off, 64); if (o0 < k0) k0 = o0;
            u64 o1 = __shfl_xor(k1, off, 64); if (o1 < k1) k1 = o1;
        }
        if ((tid & 63) == 0) { wred[tid >> 6][0] = k0; wred[tid >> 6][1] = k1; }
        __syncthreads();
        if (tid == 0) {
            u64 b0 = wred[0][0], b1 = wred[0][1];
#pragma unroll
            for (int w = 1; w < 4; ++w) {
                if (wred[w][0] < b0) b0 = wred[w][0];
                if (wred[w][1] < b1) b1 = wred[w][1];
            }
            int i0 = (int)(b0 & 0xffffffffull);
            out_idx[q0] = i0; atomicAdd(&counts[i0], 1);
            if (nq > 1) {
                int i1 = (int)(b1 & 0xffffffffull);
                out_idx[q1] = i1; atomicAdd(&counts[i1], 1);
            }
        }
        __syncthreads();
    }
}

// ---------------- K5: gather emb[idx] into [B,C,T,H,W] layout ----------------
__global__ void k_gather(const int* __restrict__ idx, const float* __restrict__ emb,
                         float* __restrict__ fh) {
    int n = blockIdx.x * 256 + threadIdx.x;   // 16384
    int id = idx[n];
    int b = n >> 13, p = n & (PLANE - 1);
    const float4* row = (const float4*)(emb + id * CDIM);
    float* dst = fh + b * BSTR + p;
#pragma unroll
    for (int r = 0; r < 8; ++r) {
        float4 v = row[r];
        dst[(r * 4 + 0) * PLANE] = v.x;
        dst[(r * 4 + 1) * PLANE] = v.y;
        dst[(r * 4 + 2) * PLANE] = v.z;
        dst[(r * 4 + 3) * PLANE] = v.w;
    }
}

// ---------------- K6: fused conv3x3x3 + blend + fhat store + loss ----------------
__global__ __launch_bounds__(256) void k_conv(const float* __restrict__ fh,
                                              const float* __restrict__ cw,
                                              const float* __restrict__ bias,
                                              const float* __restrict__ f,
                                              float* __restrict__ out,
                                              float* __restrict__ loss_sum) {
    const int tid = threadIdx.x;
    const int n = (blockIdx.x & 63) * 256 + tid;   // 0..16383
    const int cog = blockIdx.x >> 6;               // 0..7
    const int b = n >> 13, p = n & (PLANE - 1);
    const int t = p >> 10, h = (p >> 5) & 31, wi = p & 31;

    float msk[27];
#pragma unroll
    for (int dt = 0; dt < 3; ++dt)
#pragma unroll
        for (int dh = 0; dh < 3; ++dh)
#pragma unroll
            for (int dw = 0; dw < 3; ++dw) {
                bool ok = ((unsigned)(t + dt - 1) < 8u) &&
                          ((unsigned)(h + dh - 1) < 32u) &&
                          ((unsigned)(wi + dw - 1) < 32u);
                msk[dt * 9 + dh * 3 + dw] = ok ? 1.0f : 0.0f;
            }

    const float* xb = fh + b * BSTR + p;
    const float* wp = cw + cog * 4 * 864;
    float acc[4] = {0.f, 0.f, 0.f, 0.f};

    for (int ci = 0; ci < CDIM; ++ci) {
        const float* xr = xb + ci * PLANE;
        const float* x0 = xr - 1024;
        const float* x1 = xr;
        const float* x2 = xr + 1024;
#pragma unroll
        for (int dt = 0; dt < 3; ++dt) {
            const float* xp = (dt == 0) ? x0 : ((dt == 1) ? x1 : x2);
#pragma unroll
            for (int dh = 0; dh < 3; ++dh) {
#pragma unroll
                for (int dw = 0; dw < 3; ++dw) {
                    int u = dt * 9 + dh * 3 + dw;
                    float x = xp[(dh - 1) * 32 + (dw - 1)] * msk[u];
#pragma unroll
                    for (int k = 0; k < 4; ++k)
                        acc[k] = fmaf(wp[k * 864 + ci * 27 + u], x, acc[k]);
                }
            }
        }
    }

    float s = 0.f;
#pragma unroll
    for (int k = 0; k < 4; ++k) {
        int co = cog * 4 + k;
        long off = (long)b * BSTR + (long)co * PLANE + p;
        float fhc = fh[off];
        float fv = f[off];
        float o = 0.5f * fhc + 0.5f * (acc[k] + bias[co]);
        out[off] = o;
        float d = o - fv;
        s = fmaf(d, d, s);
    }
#pragma unroll
    for (int off = 32; off > 0; off >>= 1) s += __shfl_down(s, off, 64);
    __shared__ float ls[4];
    if ((tid & 63) == 0) ls[tid >> 6] = s;
    __syncthreads();
    if (tid == 0) atomicAdd(loss_sum, ls[0] + ls[1] + ls[2] + ls[3]);
}

// ---------------- K7: scalars (vq_loss, vocab_usage) ----------------
__global__ void k_scalars(const int* __restrict__ counts,
                          const float* __restrict__ loss_sum, float* __restrict__ out) {
    int tid = threadIdx.x;
    int used = 0;
#pragma unroll
    for (int r = 0; r < 32; ++r) used += (counts[tid + 256 * r] > 0) ? 1 : 0;
#pragma unroll
    for (int off = 32; off > 0; off >>= 1) used += __shfl_down(used, off, 64);
    __shared__ int us[4];
    if ((tid & 63) == 0) us[tid >> 6] = used;
    __syncthreads();
    if (tid == 0) {
        int u = us[0] + us[1] + us[2] + us[3];
        out[NEL + 0] = 1.25f * (*loss_sum) / (float)NEL;
        out[NEL + 1] = ((float)u / (float)VSZ) * 100.0f;
    }
}

extern "C" void kernel_launch(void* const* d_in, const int* in_sizes, int n_in,
                              void* d_out, int out_size, void* d_ws, size_t ws_size,
                              hipStream_t stream) {
    const float* f      = (const float*)d_in[0];
    const float* emb    = (const float*)d_in[1];
    const float* conv_w = (const float*)d_in[2];
    const float* conv_b = (const float*)d_in[3];
    float* out = (float*)d_out;
    float* ws = (float*)d_ws;

    // workspace layout (float offsets); total 1,229,056 floats (~4.9 MB)
    float* enorm    = ws;                          // 8192
    int*   counts   = (int*)(ws + 8192);           // 8192
    int*   idxb     = (int*)(ws + 16384);          // 16384
    float* loss_sum = ws + 32768;                  // 1
    int*   uct      = (int*)(ws + 32769);          // 1
    int*   flag     = (int*)(ws + 32770);          // 1 (+pad)
    int*   ulist    = (int*)(ws + 32772);          // 16384
    u16*   EFh      = (u16*)(ws + 49408);          // 131072 f (512K ushort)
    u16*   EFl      = (u16*)(ws + 180480);         // 131072 f
    u16*   QFh      = (u16*)(ws + 311552);         // 262144 f
    u16*   QFl      = (u16*)(ws + 573696);         // 262144 f
    u64*   PARTK    = (u64*)(ws + 835840);         // 262144 f (8 x 16384 u64)
    float* PARTM2   = ws + 1097984;                // 131072 f
    // fh aliased over EF/QF (dead after k_mfma/k_exact); 2048-float guard
    // margins on both sides land on finite bf16-packed bits (never NaN).
    float* fh       = ws + 49408 + 2048;

    k_prep   <<<416, 256, 0, stream>>>(f, emb, EFh, EFl, QFh, QFl, enorm, counts,
                                       loss_sum, uct, flag);
    k_mfma   <<<2049, 64, 0, stream>>>(QFh, QFl, EFh, EFl, enorm, PARTK, PARTM2,
                                       f, emb, flag);
    k_final  <<<64, 256, 0, stream>>>(PARTK, PARTM2, idxb, counts, uct, ulist, flag);
    k_exact  <<<128, 256, 0, stream>>>(ulist, uct, f, emb, enorm, idxb, counts);
    k_gather <<<64, 256, 0, stream>>>(idxb, emb, fh);
    k_conv   <<<512, 256, 0, stream>>>(fh, conv_w, conv_b, f, out, loss_sum);
    k_scalars<<<1, 256, 0, stream>>>(counts, loss_sum, out);
}